// Round 3
// 4627.382 us; speedup vs baseline: 1.0824x; 1.0824x over previous
//
#include <hip/hip_runtime.h>
#include <cmath>

// RNN with Dale's-law recurrent matrix, B=128, S=2000, H=512, I=8, O=2.
// 16 persistent blocks = 8 batch-groups (M=16) x 2 j-slices (256 j each), 512 thr.
// Round 1 (XCD-local protocol) hung; round 2 (3 bundled deltas) NaN'd.
// BISECT ROUND: base is the bit-exact proven round-0 kernel (5008us, passed).
// ONE delta only:
//   (a) deferred out-GEMM: wave 7 (c==0) computes out row s-1 from ldsA[cur^1]
//       at the TOP of the loop (hidden under the flag-wait window), row 1999 in
//       a post-loop epilogue. ldsA[cur^1] holds complete r_{s-1} at loop top
//       (own half from D(s-2), peer half from step s-1's pre-barB write); the
//       step-s D writes to that buffer are gated behind barB(s), which wave 7
//       reaches only after its reads are consumed. Out-stores issued at the top
//       are drained by the poll's vmcnt(0) flag-read wait. No counted waits.
// Everything else identical to round 0: full-drain __syncthreads at barB,
// noise prefetch -> poll -> peer load order, single-buffer ldsIN written
// between the vmcnt(0) wait and barB, unpadded flag layout.

constexpr int kS = 2000, kI = 8, kH = 512, kO = 2;
constexpr float kNoiseStd = 0.0005f, kAlpha = 0.1f;

constexpr int GROUPS = 8;   // batch groups of 16
constexpr int NSPL   = 2;   // j-slices (blocks) per group
constexpr int JS     = 256; // j per block
constexpr int NTHR   = 512; // 8 waves; wave w owns j in [w*32, w*32+32)
constexpr int NBLK   = GROUPS * NSPL;  // 16 blocks
constexpr int RSLOT  = 8192;           // halves per (slot,group) = 16KB

typedef _Float16 half8  __attribute__((ext_vector_type(8)));
typedef float    floatx4 __attribute__((ext_vector_type(4)));
typedef unsigned uintx4  __attribute__((ext_vector_type(4)));

#define MFMA16(A, B, C) __builtin_amdgcn_mfma_f32_16x16x32_f16((A), (B), (C), 0, 0, 0)
#define PIN8(a) asm volatile("" : "+v"((a)[0]), "+v"((a)[1]), "+v"((a)[2]), "+v"((a)[3]), \
                                   "+v"((a)[4]), "+v"((a)[5]), "+v"((a)[6]), "+v"((a)[7]))

static __device__ __forceinline__ unsigned ld_flag(const unsigned* p) {
  return __hip_atomic_load(p, __ATOMIC_RELAXED, __HIP_MEMORY_SCOPE_AGENT);
}
static __device__ __forceinline__ void st_flag(unsigned* p, unsigned v) {
  __hip_atomic_store(p, v, __ATOMIC_RELAXED, __HIP_MEMORY_SCOPE_AGENT);
}

// tanh(x) = sign(x) * (1 - 2/(exp2(2*log2e*|x|)+1)); overflow saturates to 1.
static __device__ __forceinline__ float fast_tanh(float x) {
  const float ax = __builtin_fabsf(x);
  const float e = __builtin_amdgcn_exp2f(2.8853900817779268f * ax);
  const float r = __builtin_amdgcn_rcpf(e + 1.0f);
  return __builtin_copysignf(__builtin_fmaf(-2.0f, r, 1.0f), x);
}

__global__ __launch_bounds__(NTHR, 1) void rnn_k(
    const float* __restrict__ inp,   // [B,S,I]
    const float* __restrict__ noise, // [B,S,H]
    const float* __restrict__ wi,    // [I,H]
    const float* __restrict__ wexc,  // [384,H]
    const float* __restrict__ winh,  // [128,H]
    const float* __restrict__ wout,  // [H,O]
    const float* __restrict__ h0,    // [H]
    float* __restrict__ out,         // [B,S,O]
    _Float16* __restrict__ rbuf,     // [2][GROUPS][RSLOT]
    unsigned* __restrict__ flags)    // [2][GROUPS][NSPL]
{
  const int bid = blockIdx.x;
  const int g = bid & 7;        // batch group
  const int c = bid >> 3;       // j-slice index (0 or 1)
  const int tid = threadIdx.x;
  const int w = tid >> 6;       // wave (0..7)
  const int lane = tid & 63;
  const int l15 = lane & 15;
  const int lhi = lane >> 4;

  const int j0 = c * JS + w * 32 + l15;  // this lane's two output columns
  const int j1 = j0 + 16;
  const int ktp = c * 8 + w;             // this wave's kt chunk in the r layout
  const int jsub0 = l15 >> 3, jsub1 = 2 + (l15 >> 3), vv = l15 & 7;

  __shared__ _Float16 ldsA[2][RSLOT];    // 32KB double-buffered A-tile
  __shared__ half8 ws_wout[16][64];      // 16KB (used by c==0)
  __shared__ float ldsIN[16][kI];        // inp rows for current step

  // ---- wrec B-fragments in registers, own/peer k-half, static indices only ----
  half8 wfo0[8], wfo1[8], wfp0[8], wfp1[8];
  {
    const float* wr0 = (j0 < 384) ? (wexc + (size_t)j0 * kH) : (winh + (size_t)(j0 - 384) * kH);
    const float* wr1 = (j1 < 384) ? (wexc + (size_t)j1 * kH) : (winh + (size_t)(j1 - 384) * kH);
    const int ko = (c * 8) * 32 + lhi * 8;
    const int kp = ((c ^ 1) * 8) * 32 + lhi * 8;
#pragma unroll
    for (int t = 0; t < 8; ++t) {
      half8 a, b, d, e;
#pragma unroll
      for (int v = 0; v < 8; ++v) {
        a[v] = (_Float16)wr0[ko + t * 32 + v];
        b[v] = (_Float16)wr1[ko + t * 32 + v];
        d[v] = (_Float16)wr0[kp + t * 32 + v];
        e[v] = (_Float16)wr1[kp + t * 32 + v];
      }
      wfo0[t] = a; wfo1[t] = b; wfp0[t] = d; wfp1[t] = e;
    }
    PIN8(wfo0); PIN8(wfo1); PIN8(wfp0); PIN8(wfp1);
  }

  float wiv0[8], wiv1[8];
#pragma unroll
  for (int i = 0; i < 8; ++i) { wiv0[i] = wi[i * kH + j0]; wiv1[i] = wi[i * kH + j1]; }

  if (c == 0 && w < 4) {
#pragma unroll
    for (int t = 0; t < 4; ++t) {
      const int kt = w * 4 + t;
      const int k0 = kt * 32 + lhi * 8;
      half8 hv;
#pragma unroll
      for (int v = 0; v < 8; ++v)
        hv[v] = (l15 < kO) ? (_Float16)wout[(size_t)(k0 + v) * kO + l15] : (_Float16)0.f;
      ws_wout[kt][lane] = hv;
    }
  }

  // ---- init h, write r_0 (own LDS chunk), publish own 1KB chunk ----
  float hq0[4], hq1[4];
  {
    const float h00 = h0[j0], h01 = h0[j1];
#pragma unroll
    for (int q = 0; q < 4; ++q) { hq0[q] = h00; hq1[q] = h01; }
    const _Float16 r00 = (_Float16)fast_tanh(h00);
    const _Float16 r01 = (_Float16)fast_tanh(h01);
#pragma unroll
    for (int q = 0; q < 4; ++q) {
      const int bb = lhi * 4 + q;
      ldsA[0][ktp * 512 + (bb + 16 * jsub0) * 8 + vv] = r00;
      ldsA[0][ktp * 512 + (bb + 16 * jsub1) * 8 + vv] = r01;
    }
    const uintx4 pub = *(const uintx4*)((const char*)&ldsA[0][0] + ktp * 1024 + lane * 16);
    char* dst = (char*)rbuf + (size_t)(0 * GROUPS + g) * (RSLOT * 2) + ktp * 1024 + lane * 16;
    asm volatile("global_store_dwordx4 %0, %1, off sc0 sc1" :: "v"(dst), "v"(pub) : "memory");
  }
  __syncthreads();  // drains vmcnt(0): publish complete
  if (tid == 0) st_flag(&flags[(0 * GROUPS + g) * NSPL + c], 1u);

  // ---- main loop ----
  for (int s = 0; s < kS; ++s) {
    const int cur = s & 1;
    const bool lastS = (s == kS - 1);
    if (lastS && c != 0) break;  // c==1 published r_1999 at iter 1998; done

    // DELTA (a): deferred out-GEMM. Row s-1 from ldsA[cur^1], which holds the
    // complete r_{s-1} at loop top. Step-s D writes to this buffer are behind
    // barB(s); wave 7 reaches barB only after these reads are consumed.
    if (c == 0 && w == 7 && s > 0) {
      floatx4 oa = {0,0,0,0}, ob = {0,0,0,0};
      const char* bprev = (const char*)&ldsA[cur ^ 1][0];
#pragma unroll
      for (int kt = 0; kt < 16; kt += 2) {
        const half8 f0 = *(const half8*)(bprev + kt * 1024 + lane * 16);
        const half8 f1 = *(const half8*)(bprev + (kt + 1) * 1024 + lane * 16);
        oa = MFMA16(f0, ws_wout[kt][lane], oa);
        ob = MFMA16(f1, ws_wout[kt + 1][lane], ob);
      }
      if (l15 < kO) {
#pragma unroll
        for (int q = 0; q < 4; ++q)
          out[((size_t)(g * 16 + lhi * 4 + q) * kS + (s - 1)) * kO + l15] = oa[q] + ob[q];
      }
    }

    // prefetch noise + input (consumed in D-phase; issued before poll)
    float nz0[4], nz1[4];
    float inv = 0.f;
    if (!lastS) {
#pragma unroll
      for (int q = 0; q < 4; ++q) {
        const int b = g * 16 + lhi * 4 + q;
        nz0[q] = noise[((size_t)b * kS + s) * kH + j0];
        nz1[q] = noise[((size_t)b * kS + s) * kH + j1];
      }
      if (w == 2 || w == 3) {
        const int ii = tid - 128;
        inv = inp[((size_t)(g * 16 + (ii >> 3)) * kS + s) * kI + (ii & 7)];
      }
    }

    // poll single peer flag (>= s+1)
    {
      const unsigned need = (unsigned)(s + 1);
      const unsigned* fp = &flags[(cur * GROUPS + g) * NSPL + (c ^ 1)];
      while (ld_flag(fp) < need) {}
      asm volatile("" ::: "memory");
    }

    // issue peer 16B load (in flight during own-half MFMAs)
    uintx4 pv;
    {
      const char* src = (const char*)rbuf + (size_t)(cur * GROUPS + g) * (RSLOT * 2)
                        + (c ^ 1) * 8192 + tid * 16;
      asm volatile("global_load_dwordx4 %0, %1, off sc0 sc1" : "=&v"(pv) : "v"(src) : "memory");
    }

    // A-phase: own k-half (8 kt) from LDS; weight regs statically indexed
    floatx4 a00 = {0,0,0,0}, a01 = {0,0,0,0}, a10 = {0,0,0,0}, a11 = {0,0,0,0};
    const char* base = (const char*)&ldsA[cur][0];
    const char* baseO = base + c * 8192;
    const char* baseP = base + (c ^ 1) * 8192;
#pragma unroll
    for (int t = 0; t < 8; t += 2) {
      const half8 f0 = *(const half8*)(baseO + t * 1024 + lane * 16);
      const half8 f1 = *(const half8*)(baseO + (t + 1) * 1024 + lane * 16);
      a00 = MFMA16(f0, wfo0[t], a00);
      a10 = MFMA16(f0, wfo1[t], a10);
      a01 = MFMA16(f1, wfo0[t + 1], a01);
      a11 = MFMA16(f1, wfo1[t + 1], a11);
    }
    __builtin_amdgcn_sched_barrier(0);
    asm volatile("s_waitcnt vmcnt(0)" : "+v"(pv) :: "memory");
    *(uintx4*)((char*)&ldsA[cur][0] + (c ^ 1) * 8192 + tid * 16) = pv;
    if (!lastS && (w == 2 || w == 3)) {
      const int ii = tid - 128;
      ldsIN[ii >> 3][ii & 7] = inv;
    }
    __syncthreads();  // barB: peer half of A-tile complete in LDS

    // C-phase: peer k-half (8 kt)
#pragma unroll
    for (int t = 0; t < 8; t += 2) {
      const half8 f0 = *(const half8*)(baseP + t * 1024 + lane * 16);
      const half8 f1 = *(const half8*)(baseP + (t + 1) * 1024 + lane * 16);
      a00 = MFMA16(f0, wfp0[t], a00);
      a10 = MFMA16(f0, wfp1[t], a10);
      a01 = MFMA16(f1, wfp0[t + 1], a01);
      a11 = MFMA16(f1, wfp1[t + 1], a11);
    }

    // D-phase: h update, write r_{s+1} (own LDS chunk), publish own chunk
    if (!lastS) {
      _Float16* lA = &ldsA[cur ^ 1][0];
#pragma unroll
      for (int q = 0; q < 4; ++q) {
        const int bb = lhi * 4 + q;
        const floatx4 iv0 = *(const floatx4*)&ldsIN[bb][0];
        const floatx4 iv1 = *(const floatx4*)&ldsIN[bb][4];
        float x0 = 0.f, x1 = 0.f;
#pragma unroll
        for (int i = 0; i < 4; ++i) {
          x0 = fmaf(iv0[i], wiv0[i], x0); x0 = fmaf(iv1[i], wiv0[i + 4], x0);
          x1 = fmaf(iv0[i], wiv1[i], x1); x1 = fmaf(iv1[i], wiv1[i + 4], x1);
        }
        const float y0 = a00[q] + a01[q], y1 = a10[q] + a11[q];
        const float h0n = hq0[q] + kNoiseStd * nz0[q] + kAlpha * (-hq0[q] + y0 + x0);
        const float h1n = hq1[q] + kNoiseStd * nz1[q] + kAlpha * (-hq1[q] + y1 + x1);
        hq0[q] = h0n; hq1[q] = h1n;
        lA[ktp * 512 + (bb + 16 * jsub0) * 8 + vv] = (_Float16)fast_tanh(h0n);
        lA[ktp * 512 + (bb + 16 * jsub1) * 8 + vv] = (_Float16)fast_tanh(h1n);
      }
      // publish this wave's 1KB chunk (same-wave LDS write->read; lgkm ordered)
      const uintx4 pub = *(const uintx4*)((const char*)lA + ktp * 1024 + lane * 16);
      char* dst = (char*)rbuf + (size_t)((cur ^ 1) * GROUPS + g) * (RSLOT * 2)
                  + ktp * 1024 + lane * 16;
      asm volatile("global_store_dwordx4 %0, %1, off sc0 sc1" :: "v"(dst), "v"(pub) : "memory");
    }
    __syncthreads();  // barD: drains publish stores (vmcnt 0) + LDS writes, all waves
    if (!lastS && tid == 0)
      st_flag(&flags[((cur ^ 1) * GROUPS + g) * NSPL + c], (unsigned)(s + 2));
  }

  // epilogue: out row kS-1 from ldsA[1] (= r_1999; own half from D(1998), peer
  // half from s=1999's pre-barB write; D(1999) skipped so both halves intact)
  if (c == 0 && w == 7) {
    const char* bfin = (const char*)&ldsA[(kS - 1) & 1][0];
    floatx4 oa = {0,0,0,0}, ob = {0,0,0,0};
#pragma unroll
    for (int kt = 0; kt < 16; kt += 2) {
      const half8 f0 = *(const half8*)(bfin + kt * 1024 + lane * 16);
      const half8 f1 = *(const half8*)(bfin + (kt + 1) * 1024 + lane * 16);
      oa = MFMA16(f0, ws_wout[kt][lane], oa);
      ob = MFMA16(f1, ws_wout[kt + 1][lane], ob);
    }
    if (l15 < kO) {
#pragma unroll
      for (int q = 0; q < 4; ++q)
        out[((size_t)(g * 16 + lhi * 4 + q) * kS + (kS - 1)) * kO + l15] = oa[q] + ob[q];
    }
  }
}

extern "C" void kernel_launch(void* const* d_in, const int* in_sizes, int n_in,
                              void* d_out, int out_size, void* d_ws, size_t ws_size,
                              hipStream_t stream) {
  const float* inp   = (const float*)d_in[0];
  const float* noise = (const float*)d_in[1];
  const float* wi    = (const float*)d_in[2];
  const float* wexc  = (const float*)d_in[3];
  const float* winh  = (const float*)d_in[4];
  const float* wout  = (const float*)d_in[5];
  const float* h0    = (const float*)d_in[6];

  _Float16* rbuf = (_Float16*)d_ws;  // 2 slots x 8 groups x 16KB = 256KB
  const size_t rbytes = (size_t)2 * GROUPS * RSLOT * sizeof(_Float16);
  unsigned* flags = (unsigned*)((char*)d_ws + rbytes);  // 32 words

  hipMemsetAsync(flags, 0, 2 * GROUPS * NSPL * sizeof(unsigned), stream);
  rnn_k<<<NBLK, NTHR, 0, stream>>>(inp, noise, wi, wexc, winh, wout, h0,
                                   (float*)d_out, rbuf, flags);
}